// Round 3
// baseline (1530.230 us; speedup 1.0000x reference)
//
#include <hip/hip_runtime.h>
#include <hip/hip_fp16.h>
#include <math.h>

#define N_MEMBERS 2
#define N_NODES   65536
#define N_EDGES   1048576
#define N_LAYERS  12
#define D         64
#define OFF_STRIDE (N_NODES + 1)
#define NODE_MASK (N_NODES - 1)

// CSR build via dst-binned counting sort
#define NBINS       256          // bin = dst >> 8 (256 nodes per bin)
#define BIN_CAP     5120         // mean 4096, +16 sigma slack
#define EDGES_PER_WG 4096        // 256 threads x 16 edges

typedef _Float16 f16;
typedef f16   f16x8 __attribute__((ext_vector_type(8)));
typedef float f32x4 __attribute__((ext_vector_type(4)));

// ---------- preprocessing: binned CSR build ----------

// Pass 1: scatter edges into per-bin staging regions with chunk reservation.
// Packed word: (src << 8) | (dst & 255)  -- 24 bits used.
__global__ __launch_bounds__(256) void bin_scatter_k(const int* __restrict__ ei,
                                                     int* __restrict__ binCursor,
                                                     unsigned int* __restrict__ binned) {
    int m = blockIdx.y;
    int t = threadIdx.x;
    int eBase = blockIdx.x * EDGES_PER_WG;
    __shared__ int hist[NBINS];
    __shared__ int base[NBINS];
    hist[t] = 0;
    __syncthreads();
    const int* srcp = ei + (size_t)(m * 2 + 0) * N_EDGES;
    const int* dstp = ei + (size_t)(m * 2 + 1) * N_EDGES;
    unsigned int pk[16];
    int bn[16], rk[16];
    #pragma unroll
    for (int i = 0; i < 16; i++) {
        int e = eBase + i * 256 + t;            // coalesced
        int src = srcp[e] & NODE_MASK;
        int dst = dstp[e] & NODE_MASK;
        int b = dst >> 8;
        bn[i] = b;
        pk[i] = ((unsigned)src << 8) | (unsigned)(dst & 255);
        rk[i] = atomicAdd(&hist[b], 1);         // local rank within WG's bin chunk
    }
    __syncthreads();
    base[t] = atomicAdd(&binCursor[m * NBINS + t], hist[t]);  // 256 global atomics/WG
    __syncthreads();
    unsigned int* bb = binned + (size_t)m * NBINS * BIN_CAP;
    #pragma unroll
    for (int i = 0; i < 16; i++) {
        int pos = base[bn[i]] + rk[i];
        if (pos < BIN_CAP)                       // overflow guard (16-sigma, never hit)
            bb[(size_t)bn[i] * BIN_CAP + pos] = pk[i];
    }
}

// Pass 2: exclusive scan of bin totals -> global bin bases.
__global__ __launch_bounds__(256) void scan_bins_k(const int* __restrict__ cur,
                                                   int* __restrict__ bbase) {
    int m = blockIdx.x, t = threadIdx.x;
    __shared__ int sh[256];
    int v0 = cur[m * NBINS + t];
    sh[t] = v0;
    __syncthreads();
    for (int ofs = 1; ofs < 256; ofs <<= 1) {
        int v = sh[t];
        int a = (t >= ofs) ? sh[t - ofs] : 0;
        __syncthreads();
        sh[t] = v + a;
        __syncthreads();
    }
    bbase[m * NBINS + t] = sh[t] - v0;   // exclusive
}

// Pass 3: one WG per bin. Coalesced read of the bin's edges; per-node degree,
// rank and exclusive scan via LDS only; dinv/off written coalesced; the 2B CSR
// scatter stays inside one ~8KB window (L2-merged).
__global__ __launch_bounds__(256) void bin_build_k(const unsigned int* __restrict__ binned,
                                                   const int* __restrict__ binCursor,
                                                   const int* __restrict__ bbase,
                                                   int* __restrict__ off,
                                                   float* __restrict__ dinv,
                                                   unsigned short* __restrict__ csr_src) {
    int m = blockIdx.y, b = blockIdx.x, t = threadIdx.x;
    int cnt   = binCursor[m * NBINS + b];
    int gbase = bbase[m * NBINS + b];
    const unsigned int* bb = binned + ((size_t)m * NBINS + b) * BIN_CAP;
    __shared__ int degl[256];
    __shared__ int offl[256];
    degl[t] = 0;
    __syncthreads();
    unsigned int ed[20];                          // rank<<24 | src<<8 | dstLow
    #pragma unroll
    for (int j = 0; j < 20; j++) {
        int i = t + j * 256;                      // coalesced
        ed[j] = 0;
        if (i < cnt) {
            unsigned int w = bb[i];
            int r = atomicAdd(&degl[w & 255], 1); // within-node rank (LDS)
            ed[j] = w | ((unsigned)r << 24);
        }
    }
    __syncthreads();
    int myDeg = degl[t];
    offl[t] = myDeg;
    __syncthreads();
    for (int ofs = 1; ofs < 256; ofs <<= 1) {     // inclusive scan
        int v = offl[t];
        int a = (t >= ofs) ? offl[t - ofs] : 0;
        __syncthreads();
        offl[t] = v + a;
        __syncthreads();
    }
    int myOff = gbase + offl[t] - myDeg;          // global exclusive offset
    int node = b * 256 + t;
    off[m * OFF_STRIDE + node] = myOff;
    if (b == NBINS - 1 && t == 255) off[m * OFF_STRIDE + N_NODES] = N_EDGES;
    dinv[m * N_NODES + node] = 1.0f / sqrtf((float)myDeg + 1.0f);
    offl[t] = myOff;
    __syncthreads();
    unsigned short* cs = csr_src + (size_t)m * N_EDGES;
    #pragma unroll
    for (int j = 0; j < 20; j++) {
        int i = t + j * 256;
        if (i < cnt) {
            int dl  = ed[j] & 255;
            int src = (ed[j] >> 8) & 0xFFFF;
            int r   = ed[j] >> 24;
            cs[offl[dl] + r] = (unsigned short)src;   // within ~8KB window
        }
    }
}

// ---------- per-layer GEMM via MFMA, split-fp16; epilogue scales by dinv -----
// tbuf[n] = fp16( dinv[n] * (h @ W)[n] )
__device__ __forceinline__ void split8(const float* p, f16x8& hi, f16x8& lo) {
    float4 a = *(const float4*)p;
    float4 b = *(const float4*)(p + 4);
    float v[8] = {a.x, a.y, a.z, a.w, b.x, b.y, b.z, b.w};
    #pragma unroll
    for (int i = 0; i < 8; i++) {
        f16 h = (f16)v[i];
        hi[i] = h;
        lo[i] = (f16)(v[i] - (float)h);
    }
}

__global__ __launch_bounds__(256) void gemm_mfma_k(const float* __restrict__ h,
                                                   const float* __restrict__ Wall,
                                                   const float* __restrict__ dinv,
                                                   __half* __restrict__ hw, int layer) {
    int m = blockIdx.y;
    const float* Wg = Wall + (size_t)(m * N_LAYERS + layer) * D * D;
    __shared__ __align__(16) _Float16 Whi[D][72];
    __shared__ __align__(16) _Float16 Wlo[D][72];
    for (int idx = threadIdx.x; idx < D * D / 4; idx += 256) {
        float4 v = ((const float4*)Wg)[idx];
        int k  = idx >> 4;
        int c0 = (idx & 15) << 2;
        float vv[4] = {v.x, v.y, v.z, v.w};
        #pragma unroll
        for (int i = 0; i < 4; i++) {
            f16 hi = (f16)vv[i];
            Whi[c0 + i][k] = hi;
            Wlo[c0 + i][k] = (f16)(vv[i] - (float)hi);
        }
    }
    __syncthreads();

    int lane = threadIdx.x & 63;
    int wav  = threadIdx.x >> 6;
    int nn   = lane & 15;
    int quad = lane >> 4;

    f16x8 Bh[8], Bl[8];
    #pragma unroll
    for (int t = 0; t < 4; t++)
        #pragma unroll
        for (int s = 0; s < 2; s++) {
            Bh[t * 2 + s] = *(const f16x8*)&Whi[t * 16 + nn][s * 32 + quad * 8];
            Bl[t * 2 + s] = *(const f16x8*)&Wlo[t * 16 + nn][s * 32 + quad * 8];
        }

    const float* hm = h + (size_t)m * N_NODES * D;
    const float* dm = dinv + m * N_NODES;
    __half*      om = hw + (size_t)m * N_NODES * D;
    int base = blockIdx.x * 256 + wav * 64;
    for (int g = 0; g < 4; g++) {
        int n0 = base + g * 16;
        const float* hrow = hm + (size_t)(n0 + nn) * D;
        f16x8 ah[2], al[2];
        split8(hrow + quad * 8,      ah[0], al[0]);
        split8(hrow + 32 + quad * 8, ah[1], al[1]);
        float dvr[4];
        #pragma unroll
        for (int r = 0; r < 4; r++) dvr[r] = dm[n0 + quad * 4 + r];
        #pragma unroll
        for (int t = 0; t < 4; t++) {
            f32x4 c = {0.f, 0.f, 0.f, 0.f};
            #pragma unroll
            for (int s = 0; s < 2; s++) {
                c = __builtin_amdgcn_mfma_f32_16x16x32_f16(ah[s], Bh[t*2+s], c, 0, 0, 0);
                c = __builtin_amdgcn_mfma_f32_16x16x32_f16(al[s], Bh[t*2+s], c, 0, 0, 0);
                c = __builtin_amdgcn_mfma_f32_16x16x32_f16(ah[s], Bl[t*2+s], c, 0, 0, 0);
            }
            #pragma unroll
            for (int r = 0; r < 4; r++)
                om[(size_t)(n0 + quad * 4 + r) * D + t * 16 + nn] =
                    __float2half((float)c[r] * dvr[r]);
        }
    }
}

// ---------- per-layer aggregate: feature-split, XCD-partitioned, nt streams --
// Job j = (member m, feature-half fh). Each job's gather hot-set is 4 MB
// (half-rows of one member's tbuf) and is pinned to XCD pair {2j, 2j+1} via
// blockIdx round-robin encoding (perf heuristic only; correctness-neutral).
// Per wave: one node-half; 8 edges in flight (sub = lane>>3, fg = lane&7).
// out[n] = dinv[n] * (sum_{s in N(n)} hws[s] + hws[n]) + b   [; relu]
__device__ __forceinline__ float4 cvt4(ushort4 u) {
    union { ushort2 us[2]; __half2 h2[2]; } c;
    c.us[0] = make_ushort2(u.x, u.y);
    c.us[1] = make_ushort2(u.z, u.w);
    float2 a = __half22float2(c.h2[0]);
    float2 b = __half22float2(c.h2[1]);
    return make_float4(a.x, a.y, b.x, b.y);
}

__global__ __launch_bounds__(256) void aggregate_k(const __half* __restrict__ hw,
                                                   float* __restrict__ out,
                                                   const int* __restrict__ off,
                                                   const unsigned short* __restrict__ csr_src,
                                                   const float* __restrict__ dinv,
                                                   const float* __restrict__ ball,
                                                   int layer, int relu) {
    int b  = blockIdx.x;
    // decode: b = (k>>1)*8 + 2*j + (k&1)  ->  job j on XCDs {2j, 2j+1}
    int j  = (b >> 1) & 3;
    int k  = ((b >> 3) << 1) | (b & 1);
    int m  = j >> 1;
    int fh = j & 1;
    int n  = k * 4 + (threadIdx.x >> 6);
    int lane = threadIdx.x & 63;
    int fg   = lane & 7;          // 8 x ushort4 = 32 cols (one 64B line)
    int sub  = lane >> 3;         // 8 edges in flight
    const ushort4* hm4 = (const ushort4*)(hw + (size_t)m * N_NODES * D) + fh * 8;
    const int*            ob = off + m * OFF_STRIDE;
    const unsigned short* sb = csr_src + (size_t)m * N_EDGES;

    float4 acc = make_float4(0.f, 0.f, 0.f, 0.f);
    int e0 = ob[n], e1 = ob[n + 1];
    #pragma unroll 2
    for (int e = e0; e < e1; e += 8) {
        int ee  = e + sub;
        int idx = (ee < e1) ? ee : (e1 - 1);
        int s   = __builtin_nontemporal_load(&sb[idx]);   // nt: don't pollute L2
        float w = (ee < e1) ? 1.0f : 0.0f;
        float4 g = cvt4(hm4[(size_t)s * 16 + fg]);
        acc.x = fmaf(w, g.x, acc.x);
        acc.y = fmaf(w, g.y, acc.y);
        acc.z = fmaf(w, g.z, acc.z);
        acc.w = fmaf(w, g.w, acc.w);
    }
    #pragma unroll
    for (int msk = 8; msk < 64; msk <<= 1) {
        acc.x += __shfl_xor(acc.x, msk);
        acc.y += __shfl_xor(acc.y, msk);
        acc.z += __shfl_xor(acc.z, msk);
        acc.w += __shfl_xor(acc.w, msk);
    }

    float dv  = dinv[m * N_NODES + n];
    float4 s4 = cvt4(hm4[(size_t)n * 16 + fg]);   // hws[n] (prescaled)
    float4 bi = ((const float4*)(ball + (size_t)(m * N_LAYERS + layer) * D + fh * 32))[fg];
    acc.x = fmaf(dv, acc.x + s4.x, bi.x);
    acc.y = fmaf(dv, acc.y + s4.y, bi.y);
    acc.z = fmaf(dv, acc.z + s4.z, bi.z);
    acc.w = fmaf(dv, acc.w + s4.w, bi.w);
    if (relu) {
        acc.x = fmaxf(acc.x, 0.f);
        acc.y = fmaxf(acc.y, 0.f);
        acc.z = fmaxf(acc.z, 0.f);
        acc.w = fmaxf(acc.w, 0.f);
    }
    if (lane < 8) {
        float* op = out + (size_t)m * N_NODES * D + (size_t)n * D + fh * 32 + lane * 4;
        f32x4 v = {acc.x, acc.y, acc.z, acc.w};
        __builtin_nontemporal_store(v, (f32x4*)op);       // nt: don't pollute L2
    }
}

// ---------- host ----------

extern "C" void kernel_launch(void* const* d_in, const int* in_sizes, int n_in,
                              void* d_out, int out_size, void* d_ws, size_t ws_size,
                              hipStream_t stream) {
    (void)in_sizes; (void)n_in; (void)out_size; (void)ws_size;
    const float* x  = (const float*)d_in[0];
    const int*   ei = (const int*)d_in[1];
    const float* W  = (const float*)d_in[2];
    const float* b  = (const float*)d_in[3];
    float* out = (float*)d_out;

    char* ws = (char*)d_ws;
    size_t o = 0;
    auto take = [&](size_t bytes) -> void* {
        void* p = ws + o;
        o = (o + bytes + 255) & ~(size_t)255;
        return p;
    };
    float*          dinv      = (float*) take((size_t)N_MEMBERS * N_NODES * 4);
    int*            off       = (int*)   take((size_t)N_MEMBERS * OFF_STRIDE * 4);
    int*            binCursor = (int*)   take((size_t)N_MEMBERS * NBINS * 4);
    int*            bbase     = (int*)   take((size_t)N_MEMBERS * NBINS * 4);
    unsigned short* csr_src   = (unsigned short*)take((size_t)N_MEMBERS * N_EDGES * 2);
    __half*         tbuf      = (__half*)take((size_t)N_MEMBERS * N_NODES * D * 2);
    float*          hbuf      = (float*) take((size_t)N_MEMBERS * N_NODES * D * 4);
    // binned staging (10.5 MB) aliases hbuf (32 MB): lifetimes are disjoint
    // (binned dies at bin_build_k; hbuf born at aggregate_k layer 0).
    unsigned int*   binned    = (unsigned int*)hbuf;

    hipMemsetAsync(binCursor, 0, (size_t)N_MEMBERS * NBINS * 4, stream);

    bin_scatter_k<<<dim3(N_EDGES / EDGES_PER_WG, N_MEMBERS), 256, 0, stream>>>(
        ei, binCursor, binned);
    scan_bins_k<<<dim3(N_MEMBERS), 256, 0, stream>>>(binCursor, bbase);
    bin_build_k<<<dim3(NBINS, N_MEMBERS), 256, 0, stream>>>(
        binned, binCursor, bbase, off, dinv, csr_src);

    const float* hin = x;
    for (int j = 0; j < N_LAYERS; j++) {
        gemm_mfma_k<<<dim3(N_NODES / 256, N_MEMBERS), 256, 0, stream>>>(hin, W, dinv, tbuf, j);
        float* dst = (j == N_LAYERS - 1) ? out : hbuf;
        // 4 jobs x 16384 blocks, XCD-partitioned via linear-ID encoding
        aggregate_k<<<dim3(4 * (N_NODES / 4)), 256, 0, stream>>>(
            tbuf, dst, off, csr_src, dinv, b, j, (j < N_LAYERS - 1) ? 1 : 0);
        hin = hbuf;
    }
}

// Round 4
// 911.307 us; speedup vs baseline: 1.6792x; 1.6792x over previous
//
#include <hip/hip_runtime.h>
#include <hip/hip_fp16.h>
#include <math.h>

#define N_MEMBERS 2
#define N_NODES   65536
#define N_EDGES   1048576
#define N_LAYERS  12
#define D         64
#define OFF_STRIDE (N_NODES + 1)
#define NODE_MASK (N_NODES - 1)

// CSR build via dst-binned counting sort
#define NBINS       256          // bin = dst >> 8 (256 nodes per bin)
#define BIN_CAP     5120         // mean 4096, +16 sigma slack
#define EDGES_PER_WG 4096        // 256 threads x 16 edges

typedef _Float16 f16;
typedef f16   f16x8 __attribute__((ext_vector_type(8)));
typedef float f32x4 __attribute__((ext_vector_type(4)));

// ---------- preprocessing: binned CSR build ----------

// Pass 1: scatter edges into per-bin staging regions with chunk reservation.
// Packed word: (src << 8) | (dst & 255)  -- 24 bits used.
__global__ __launch_bounds__(256) void bin_scatter_k(const int* __restrict__ ei,
                                                     int* __restrict__ binCursor,
                                                     unsigned int* __restrict__ binned) {
    int m = blockIdx.y;
    int t = threadIdx.x;
    int eBase = blockIdx.x * EDGES_PER_WG;
    __shared__ int hist[NBINS];
    __shared__ int base[NBINS];
    hist[t] = 0;
    __syncthreads();
    const int* srcp = ei + (size_t)(m * 2 + 0) * N_EDGES;
    const int* dstp = ei + (size_t)(m * 2 + 1) * N_EDGES;
    unsigned int pk[16];
    int bn[16], rk[16];
    #pragma unroll
    for (int i = 0; i < 16; i++) {
        int e = eBase + i * 256 + t;            // coalesced
        int src = srcp[e] & NODE_MASK;
        int dst = dstp[e] & NODE_MASK;
        int b = dst >> 8;
        bn[i] = b;
        pk[i] = ((unsigned)src << 8) | (unsigned)(dst & 255);
        rk[i] = atomicAdd(&hist[b], 1);         // local rank within WG's bin chunk
    }
    __syncthreads();
    base[t] = atomicAdd(&binCursor[m * NBINS + t], hist[t]);  // 256 global atomics/WG
    __syncthreads();
    unsigned int* bb = binned + (size_t)m * NBINS * BIN_CAP;
    #pragma unroll
    for (int i = 0; i < 16; i++) {
        int pos = base[bn[i]] + rk[i];
        if (pos < BIN_CAP)                       // overflow guard (16-sigma, never hit)
            bb[(size_t)bn[i] * BIN_CAP + pos] = pk[i];
    }
}

// Pass 2: exclusive scan of bin totals -> global bin bases.
__global__ __launch_bounds__(256) void scan_bins_k(const int* __restrict__ cur,
                                                   int* __restrict__ bbase) {
    int m = blockIdx.x, t = threadIdx.x;
    __shared__ int sh[256];
    int v0 = cur[m * NBINS + t];
    sh[t] = v0;
    __syncthreads();
    for (int ofs = 1; ofs < 256; ofs <<= 1) {
        int v = sh[t];
        int a = (t >= ofs) ? sh[t - ofs] : 0;
        __syncthreads();
        sh[t] = v + a;
        __syncthreads();
    }
    bbase[m * NBINS + t] = sh[t] - v0;   // exclusive
}

// Pass 3: one WG per bin. Coalesced read of the bin's edges; per-node degree,
// rank and exclusive scan via LDS only; dinv/off written coalesced; the 2B CSR
// scatter stays inside one ~8KB window (L2-merged).
__global__ __launch_bounds__(256) void bin_build_k(const unsigned int* __restrict__ binned,
                                                   const int* __restrict__ binCursor,
                                                   const int* __restrict__ bbase,
                                                   int* __restrict__ off,
                                                   float* __restrict__ dinv,
                                                   unsigned short* __restrict__ csr_src) {
    int m = blockIdx.y, b = blockIdx.x, t = threadIdx.x;
    int cnt   = binCursor[m * NBINS + b];
    int gbase = bbase[m * NBINS + b];
    const unsigned int* bb = binned + ((size_t)m * NBINS + b) * BIN_CAP;
    __shared__ int degl[256];
    __shared__ int offl[256];
    degl[t] = 0;
    __syncthreads();
    unsigned int ed[20];                          // rank<<24 | src<<8 | dstLow
    #pragma unroll
    for (int j = 0; j < 20; j++) {
        int i = t + j * 256;                      // coalesced
        ed[j] = 0;
        if (i < cnt) {
            unsigned int w = bb[i];
            int r = atomicAdd(&degl[w & 255], 1); // within-node rank (LDS)
            ed[j] = w | ((unsigned)r << 24);
        }
    }
    __syncthreads();
    int myDeg = degl[t];
    offl[t] = myDeg;
    __syncthreads();
    for (int ofs = 1; ofs < 256; ofs <<= 1) {     // inclusive scan
        int v = offl[t];
        int a = (t >= ofs) ? offl[t - ofs] : 0;
        __syncthreads();
        offl[t] = v + a;
        __syncthreads();
    }
    int myOff = gbase + offl[t] - myDeg;          // global exclusive offset
    int node = b * 256 + t;
    off[m * OFF_STRIDE + node] = myOff;
    if (b == NBINS - 1 && t == 255) off[m * OFF_STRIDE + N_NODES] = N_EDGES;
    dinv[m * N_NODES + node] = 1.0f / sqrtf((float)myDeg + 1.0f);
    offl[t] = myOff;
    __syncthreads();
    unsigned short* cs = csr_src + (size_t)m * N_EDGES;
    #pragma unroll
    for (int j = 0; j < 20; j++) {
        int i = t + j * 256;
        if (i < cnt) {
            int dl  = ed[j] & 255;
            int src = (ed[j] >> 8) & 0xFFFF;
            int r   = ed[j] >> 24;
            cs[offl[dl] + r] = (unsigned short)src;   // within ~8KB window
        }
    }
}

// ---------- per-layer GEMM via MFMA, split-fp16; epilogue scales by dinv -----
// tbuf[n] = fp16( dinv[n] * (h @ W)[n] )
__device__ __forceinline__ void split8(const float* p, f16x8& hi, f16x8& lo) {
    float4 a = *(const float4*)p;
    float4 b = *(const float4*)(p + 4);
    float v[8] = {a.x, a.y, a.z, a.w, b.x, b.y, b.z, b.w};
    #pragma unroll
    for (int i = 0; i < 8; i++) {
        f16 h = (f16)v[i];
        hi[i] = h;
        lo[i] = (f16)(v[i] - (float)h);
    }
}

__global__ __launch_bounds__(256) void gemm_mfma_k(const float* __restrict__ h,
                                                   const float* __restrict__ Wall,
                                                   const float* __restrict__ dinv,
                                                   __half* __restrict__ hw, int layer) {
    int m = blockIdx.y;
    const float* Wg = Wall + (size_t)(m * N_LAYERS + layer) * D * D;
    __shared__ __align__(16) _Float16 Whi[D][72];
    __shared__ __align__(16) _Float16 Wlo[D][72];
    for (int idx = threadIdx.x; idx < D * D / 4; idx += 256) {
        float4 v = ((const float4*)Wg)[idx];
        int k  = idx >> 4;
        int c0 = (idx & 15) << 2;
        float vv[4] = {v.x, v.y, v.z, v.w};
        #pragma unroll
        for (int i = 0; i < 4; i++) {
            f16 hi = (f16)vv[i];
            Whi[c0 + i][k] = hi;
            Wlo[c0 + i][k] = (f16)(vv[i] - (float)hi);
        }
    }
    __syncthreads();

    int lane = threadIdx.x & 63;
    int wav  = threadIdx.x >> 6;
    int nn   = lane & 15;
    int quad = lane >> 4;

    f16x8 Bh[8], Bl[8];
    #pragma unroll
    for (int t = 0; t < 4; t++)
        #pragma unroll
        for (int s = 0; s < 2; s++) {
            Bh[t * 2 + s] = *(const f16x8*)&Whi[t * 16 + nn][s * 32 + quad * 8];
            Bl[t * 2 + s] = *(const f16x8*)&Wlo[t * 16 + nn][s * 32 + quad * 8];
        }

    const float* hm = h + (size_t)m * N_NODES * D;
    const float* dm = dinv + m * N_NODES;
    __half*      om = hw + (size_t)m * N_NODES * D;
    int base = blockIdx.x * 256 + wav * 64;
    for (int g = 0; g < 4; g++) {
        int n0 = base + g * 16;
        const float* hrow = hm + (size_t)(n0 + nn) * D;
        f16x8 ah[2], al[2];
        split8(hrow + quad * 8,      ah[0], al[0]);
        split8(hrow + 32 + quad * 8, ah[1], al[1]);
        float dvr[4];
        #pragma unroll
        for (int r = 0; r < 4; r++) dvr[r] = dm[n0 + quad * 4 + r];
        #pragma unroll
        for (int t = 0; t < 4; t++) {
            f32x4 c = {0.f, 0.f, 0.f, 0.f};
            #pragma unroll
            for (int s = 0; s < 2; s++) {
                c = __builtin_amdgcn_mfma_f32_16x16x32_f16(ah[s], Bh[t*2+s], c, 0, 0, 0);
                c = __builtin_amdgcn_mfma_f32_16x16x32_f16(al[s], Bh[t*2+s], c, 0, 0, 0);
                c = __builtin_amdgcn_mfma_f32_16x16x32_f16(ah[s], Bl[t*2+s], c, 0, 0, 0);
            }
            #pragma unroll
            for (int r = 0; r < 4; r++)
                om[(size_t)(n0 + quad * 4 + r) * D + t * 16 + nn] =
                    __float2half((float)c[r] * dvr[r]);
        }
    }
}

// ---------- per-layer aggregate: full 128B rows, 8 edges in flight ----------
// One node per wave. fg = lane&7 selects the 16B chunk of the 128B fp16 row
// (dwordx4 gather), sub = lane>>3 gives 8 edges in flight; unroll 2 -> 16
// outstanding gathers per wave (2x Round-1 MLP, half the load instructions).
// out[n] = dinv[n] * (sum_{s in N(n)} hws[s] + hws[n]) + b   [; relu]
__device__ __forceinline__ void cvt8(uint4 u, float* f) {
    const __half2* h2 = (const __half2*)&u;
    #pragma unroll
    for (int i = 0; i < 4; i++) {
        float2 t = __half22float2(h2[i]);
        f[2 * i]     = t.x;
        f[2 * i + 1] = t.y;
    }
}

__global__ __launch_bounds__(256) void aggregate_k(const __half* __restrict__ hw,
                                                   float* __restrict__ out,
                                                   const int* __restrict__ off,
                                                   const unsigned short* __restrict__ csr_src,
                                                   const float* __restrict__ dinv,
                                                   const float* __restrict__ ball,
                                                   int layer, int relu) {
    int m = blockIdx.y;
    int n = blockIdx.x * 4 + (threadIdx.x >> 6);
    int lane = threadIdx.x & 63;
    int fg   = lane & 7;          // 16B chunk (8 halfs) of the 128B row
    int sub  = lane >> 3;         // 8 edges in flight
    const __half*         hm = hw + (size_t)m * N_NODES * D;
    const int*            ob = off + m * OFF_STRIDE;
    const unsigned short* sb = csr_src + (size_t)m * N_EDGES;

    float acc[8];
    #pragma unroll
    for (int i = 0; i < 8; i++) acc[i] = 0.f;

    int e0 = ob[n], e1 = ob[n + 1];
    #pragma unroll 2
    for (int e = e0; e < e1; e += 8) {
        int ee  = e + sub;
        int idx = (ee < e1) ? ee : (e1 - 1);
        int s   = sb[idx];
        float w = (ee < e1) ? 1.0f : 0.0f;
        uint4 g = *(const uint4*)(hm + (size_t)s * D + fg * 8);
        float f[8];
        cvt8(g, f);
        #pragma unroll
        for (int i = 0; i < 8; i++) acc[i] = fmaf(w, f[i], acc[i]);
    }
    #pragma unroll
    for (int msk = 8; msk < 64; msk <<= 1)
        #pragma unroll
        for (int i = 0; i < 8; i++) acc[i] += __shfl_xor(acc[i], msk);

    float dv = dinv[m * N_NODES + n];
    uint4 sg = *(const uint4*)(hm + (size_t)n * D + fg * 8);   // hws[n] (prescaled)
    float sf[8];
    cvt8(sg, sf);
    const float* bp = ball + (size_t)(m * N_LAYERS + layer) * D + fg * 8;
    #pragma unroll
    for (int i = 0; i < 8; i++) {
        acc[i] = fmaf(dv, acc[i] + sf[i], bp[i]);
        if (relu) acc[i] = fmaxf(acc[i], 0.f);
    }
    if (sub == 0) {
        float4* op = (float4*)(out + (size_t)m * N_NODES * D + (size_t)n * D + fg * 8);
        op[0] = make_float4(acc[0], acc[1], acc[2], acc[3]);
        op[1] = make_float4(acc[4], acc[5], acc[6], acc[7]);
    }
}

// ---------- host ----------

extern "C" void kernel_launch(void* const* d_in, const int* in_sizes, int n_in,
                              void* d_out, int out_size, void* d_ws, size_t ws_size,
                              hipStream_t stream) {
    (void)in_sizes; (void)n_in; (void)out_size; (void)ws_size;
    const float* x  = (const float*)d_in[0];
    const int*   ei = (const int*)d_in[1];
    const float* W  = (const float*)d_in[2];
    const float* b  = (const float*)d_in[3];
    float* out = (float*)d_out;

    char* ws = (char*)d_ws;
    size_t o = 0;
    auto take = [&](size_t bytes) -> void* {
        void* p = ws + o;
        o = (o + bytes + 255) & ~(size_t)255;
        return p;
    };
    float*          dinv      = (float*) take((size_t)N_MEMBERS * N_NODES * 4);
    int*            off       = (int*)   take((size_t)N_MEMBERS * OFF_STRIDE * 4);
    int*            binCursor = (int*)   take((size_t)N_MEMBERS * NBINS * 4);
    int*            bbase     = (int*)   take((size_t)N_MEMBERS * NBINS * 4);
    unsigned short* csr_src   = (unsigned short*)take((size_t)N_MEMBERS * N_EDGES * 2);
    __half*         tbuf      = (__half*)take((size_t)N_MEMBERS * N_NODES * D * 2);
    float*          hbuf      = (float*) take((size_t)N_MEMBERS * N_NODES * D * 4);
    // binned staging (10.5 MB) aliases hbuf (32 MB): lifetimes are disjoint
    // (binned dies at bin_build_k; hbuf born at aggregate_k layer 0).
    unsigned int*   binned    = (unsigned int*)hbuf;

    hipMemsetAsync(binCursor, 0, (size_t)N_MEMBERS * NBINS * 4, stream);

    bin_scatter_k<<<dim3(N_EDGES / EDGES_PER_WG, N_MEMBERS), 256, 0, stream>>>(
        ei, binCursor, binned);
    scan_bins_k<<<dim3(N_MEMBERS), 256, 0, stream>>>(binCursor, bbase);
    bin_build_k<<<dim3(NBINS, N_MEMBERS), 256, 0, stream>>>(
        binned, binCursor, bbase, off, dinv, csr_src);

    const float* hin = x;
    for (int j = 0; j < N_LAYERS; j++) {
        gemm_mfma_k<<<dim3(N_NODES / 256, N_MEMBERS), 256, 0, stream>>>(hin, W, dinv, tbuf, j);
        float* dst = (j == N_LAYERS - 1) ? out : hbuf;
        aggregate_k<<<dim3(N_NODES / 4, N_MEMBERS), 256, 0, stream>>>(
            tbuf, dst, off, csr_src, dinv, b, j, (j < N_LAYERS - 1) ? 1 : 0);
        hin = hbuf;
    }
}